// Round 6
// baseline (340.904 us; speedup 1.0000x reference)
//
#include <hip/hip_runtime.h>
#include <hip/hip_bf16.h>

// Problem constants (fixed by reference)
#define B_ 16
#define L_ 24
#define N_ 256
#define E_ 4096
#define T_ (B_ * L_)   // 384 graphs

// All tensors float32. Output [B,L,N,64] f32 = 25.2 MB.
// X (LSTM h states, [T,N,64] f32) lives in d_out; k_graph overwrites its own
// tile in place. ws holds folded tables only (~140 KB).
constexpr int WP    = 0;                   // P = W1a@W2b  (64x64)
constexpr int WRQ   = WP + 4096;           // R+Q = W2a + W1b@W2b (64x64)
constexpr int WRM   = WRQ + 4096;          // (unused)
constexpr int WBIAS = WRM + 4096;          // biasv [256][64]
constexpr int WALPHA= WBIAS + 16384;       // alpha[256]
constexpr int WBETA = WALPHA + 256;        // beta[256]
constexpr int WDINV = WBETA + 256;         // 1/max(cnt,1) [256]
constexpr int WSEL  = WDINV + 256;         // cnt>0 ? 1 : 0 [256]
constexpr int WSW   = WSEL + 256;          // sw0[256], sw1[256]
constexpr int WCNTF = WSW + 512;           // cnt as float [256]
constexpr int WCOLP = WCNTF + 256;         // 257 ints (CSR col ptr)
constexpr int WROWS = WCOLP + 260;         // 4096 ints (row node per edge, grouped by col)

__device__ __forceinline__ float sigm(float x) { return 1.f / (1.f + __expf(-x)); }
__device__ __forceinline__ float tanh_(float x) { return 2.f / (1.f + __expf(-2.f * x)) - 1.f; }
__device__ __forceinline__ float bcast(float v, int lane) {
    return __int_as_float(__builtin_amdgcn_readlane(__float_as_int(v), lane));
}
__device__ __forceinline__ float blo(unsigned u) { return __uint_as_float(u << 16); }
__device__ __forceinline__ float bhi(unsigned u) { return __uint_as_float(u & 0xffff0000u); }

// ---- K1 fused prep: block 0 = graph tables + alpha/beta + U + biasv;
// ----                blocks 1..8 = P / RQ weight products.
__global__ __launch_bounds__(256) void k_prep(
    const int* __restrict__ conn, const float* __restrict__ cw,
    const float* __restrict__ Wih, const float* __restrict__ embW,
    const float* __restrict__ embB, const float* __restrict__ bih,
    const float* __restrict__ bhh, const float* __restrict__ m1W,
    const float* __restrict__ m1b, const float* __restrict__ m2W,
    const float* __restrict__ m2b, float* __restrict__ ws) {
    int t = threadIdx.x, blk = blockIdx.x;
    if (blk > 0) {
        // ---- P = W1a@W2b (blk 1..4), RQ = W2a + W1b@W2b (blk 5..8) ----
        __shared__ float sB[64 * 64];   // W2b = m2W rows 64..127
        bool isP = blk <= 4;
        int kbase = ((blk - 1) & 3) * 16;
        #pragma unroll
        for (int i = 0; i < 16; ++i) sB[t + 256 * i] = m2W[64 * 64 + t + 256 * i];
        __syncthreads();
        int j = t & 63, kl = t >> 6;
        #pragma unroll
        for (int r = 0; r < 4; ++r) {
            int k = kbase + kl * 4 + r;
            const float* arow = m1W + (isP ? k : (64 + k)) * 64;
            float acc = isP ? 0.f : m2W[k * 64 + j];
            #pragma unroll
            for (int m = 0; m < 64; m += 4) {
                float4 a4 = *(const float4*)(arow + m);
                acc = fmaf(a4.x, sB[m * 64 + j], acc);
                acc = fmaf(a4.y, sB[(m + 1) * 64 + j], acc);
                acc = fmaf(a4.z, sB[(m + 2) * 64 + j], acc);
                acc = fmaf(a4.w, sB[(m + 3) * 64 + j], acc);
            }
            ws[(isP ? WP : WRQ) + k * 64 + j] = acc;
        }
        return;
    }
    // ---- block 0: tables ----
    __shared__ int s_cnt[N_];
    __shared__ float s_sw0[N_], s_sw1[N_];
    __shared__ int s_pos[N_];
    __shared__ float sU[3 * 64];
    __shared__ int s_wsum[4];
    s_cnt[t] = 0; s_sw0[t] = 0.f; s_sw1[t] = 0.f;
    __syncthreads();
    for (int e = t; e < E_; e += 256) {
        int c = conn[E_ + e] & 255;
        atomicAdd(&s_cnt[c], 1);
        atomicAdd(&s_sw0[c], cw[2 * e]);
        atomicAdd(&s_sw1[c], cw[2 * e + 1]);
    }
    __syncthreads();
    // exclusive prefix sum over 256 via wave shfl scan + wave offsets
    int lane = t & 63, wv = t >> 6;
    int val = s_cnt[t];
    int inc = val;
    #pragma unroll
    for (int d = 1; d < 64; d <<= 1) {
        int y = __shfl_up(inc, d);
        if (lane >= d) inc += y;
    }
    if (lane == 63) s_wsum[wv] = inc;
    __syncthreads();
    int wadd = 0;
    for (int w = 0; w < wv; ++w) wadd += s_wsum[w];
    int excl = wadd + inc - val;
    int* colp = (int*)(ws + WCOLP);
    colp[t] = excl;
    if (t == 0) colp[N_] = E_;
    s_pos[t] = excl;
    int cnt = val;
    ws[WCNTF + t] = (float)cnt;
    ws[WDINV + t] = 1.f / (float)(cnt > 1 ? cnt : 1);
    ws[WSEL + t]  = cnt > 0 ? 1.f : 0.f;
    ws[WSW + t]        = s_sw0[t];
    ws[WSW + N_ + t]   = s_sw1[t];
    // LSTM input collapse: xg[g] = aqi*alpha[g] + beta[g]
    float a = 0.f, b = 0.f;
    #pragma unroll
    for (int i = 0; i < 16; ++i) {
        float w = Wih[t * 16 + i];
        a += w * embW[i];
        b += w * embB[i];
    }
    ws[WALPHA + t] = a;
    ws[WBETA + t]  = b + bih[t] + bhh[t];
    __syncthreads();   // all s_pos[] initialized before rows fill
    int* rows = (int*)(ws + WROWS);
    for (int e = t; e < E_; e += 256) {
        int c = conn[E_ + e] & 255;
        int p = atomicAdd(&s_pos[c], 1);
        rows[p] = conn[e] & 255;
    }
    // U vectors: U0 = W1c0@W2b, U1 = W1c1@W2b, U2 = b1@W2b
    if (t < 192) {
        int part = t >> 6, j = t & 63;
        float acc = 0.f;
        #pragma unroll 8
        for (int m = 0; m < 64; ++m) {
            float w = (part == 0) ? m1W[128 * 64 + m]
                    : (part == 1) ? m1W[129 * 64 + m] : m1b[m];
            acc = fmaf(w, m2W[(64 + m) * 64 + j], acc);
        }
        sU[part * 64 + j] = acc;
    }
    __syncthreads();
    // biasv[v][j] = dinv_v*(sw0_v*U0[j] + sw1_v*U1[j] + cnt_v*U2[j]) + b2[j]
    {
        int j = t & 63;
        float u0 = sU[j], u1 = sU[64 + j], u2 = sU[128 + j];
        float b2j = m2b[j];
        int vb = t >> 6;
        #pragma unroll 8
        for (int i = 0; i < 64; ++i) {
            int v = vb + i * 4;
            int cv = s_cnt[v];
            float dv = 1.f / (float)(cv > 1 ? cv : 1);
            float bb = s_sw0[v] * u0 + s_sw1[v] * u1 + (float)cv * u2;
            ws[WBIAS + v * 64 + j] = dv * bb + b2j;
        }
    }
}

// ---------------- K2: LSTM. wave = 2 sequences, lane = hidden dim -----------
// h states written f32 directly into d_out (layout [B,L,N,64] == [T,N,64]).
__global__ __launch_bounds__(256, 2) void k_lstm(
    const float* __restrict__ aqi, const float* __restrict__ Whh,
    const float* __restrict__ ws, float* __restrict__ xout) {
    __shared__ float Wl[16384];   // Wl[hp*256 + j*4 + k] = W_hh[(k*64+j)*64+hp]
    int t = threadIdx.x;
    #pragma unroll
    for (int i = 0; i < 64; ++i) {
        int idx = t + i * 256;
        int hp = idx >> 8, rem = idx & 255;
        int j = rem >> 2, k = rem & 3;
        Wl[idx] = Whh[(k * 64 + j) * 64 + hp];
    }
    __syncthreads();
    int wave = t >> 6, lane = t & 63;
    int s0 = (blockIdx.x * 4 + wave) * 2;   // sequence = b*256 + n
    int bA = s0 >> 8, nA = s0 & 255;
    int bB = (s0 + 1) >> 8, nB = (s0 + 1) & 255;
    float a0 = ws[WALPHA + lane], a1 = ws[WALPHA + 64 + lane];
    float a2 = ws[WALPHA + 128 + lane], a3 = ws[WALPHA + 192 + lane];
    float e0 = ws[WBETA + lane], e1 = ws[WBETA + 64 + lane];
    float e2 = ws[WBETA + 128 + lane], e3 = ws[WBETA + 192 + lane];
    float hA = 0.f, cA = 0.f, hB = 0.f, cB = 0.f;
    for (int l = 0; l < L_; ++l) {
        float xA = aqi[(bA * L_ + l) * N_ + nA];
        float xB = aqi[(bB * L_ + l) * N_ + nB];
        float g0A = fmaf(xA, a0, e0), g1A = fmaf(xA, a1, e1);
        float g2A = fmaf(xA, a2, e2), g3A = fmaf(xA, a3, e3);
        float g0B = fmaf(xB, a0, e0), g1B = fmaf(xB, a1, e1);
        float g2B = fmaf(xB, a2, e2), g3B = fmaf(xB, a3, e3);
        if (l > 0) {
            #pragma unroll
            for (int hp = 0; hp < 64; ++hp) {
                float hvA = bcast(hA, hp);
                float hvB = bcast(hB, hp);
                const float4 w = *(const float4*)&Wl[hp * 256 + lane * 4];
                g0A = fmaf(hvA, w.x, g0A); g1A = fmaf(hvA, w.y, g1A);
                g2A = fmaf(hvA, w.z, g2A); g3A = fmaf(hvA, w.w, g3A);
                g0B = fmaf(hvB, w.x, g0B); g1B = fmaf(hvB, w.y, g1B);
                g2B = fmaf(hvB, w.z, g2B); g3B = fmaf(hvB, w.w, g3B);
            }
        }
        float iA = sigm(g0A), fA = sigm(g1A), GA = tanh_(g2A), oA = sigm(g3A);
        cA = fmaf(fA, cA, iA * GA); hA = oA * tanh_(cA);
        float iB = sigm(g0B), fB = sigm(g1B), GB = tanh_(g2B), oB = sigm(g3B);
        cB = fmaf(fB, cB, iB * GB); hB = oB * tanh_(cB);
        xout[((bA * L_ + l) * N_ + nA) * 64 + lane] = hA;
        xout[((bB * L_ + l) * N_ + nB) * 64 + lane] = hB;
    }
}

// ---------------- K4: per-graph GNN, S-space gather (no XP buffer) ----------
// out[v] = biasv + x[v]@(W2a or W2a+Q) + (dinv*S[v])@P,  S[v] = sum_in x[row].
// 512 threads/block: 2 threads per node, each owns 32 output columns.
constexpr int XS = 68;  // bf16 LDS row stride (rows 8B-aligned: 136 B)

__global__ __launch_bounds__(512, 4) void k_graph(
    const float* __restrict__ ws, const float* __restrict__ m2W,
    float* __restrict__ out) {
    __shared__ __hip_bfloat16 Xl[N_ * XS];   // 34 KB
    int tg = blockIdx.x;
    int tid = threadIdx.x;
    // stage this graph's X tile (16384 f32) into bf16 LDS
    const float4* src = (const float4*)(out + tg * (N_ * 64));
    #pragma unroll
    for (int it = 0; it < 8; ++it) {
        int idx = tid + it * 512;
        float4 d = src[idx];
        int g0 = idx * 4;
        int node = g0 >> 6, col = g0 & 63;    // col multiple of 4
        __hip_bfloat162 p0 = __halves2bfloat162(__float2bfloat16(d.x), __float2bfloat16(d.y));
        __hip_bfloat162 p1 = __halves2bfloat162(__float2bfloat16(d.z), __float2bfloat16(d.w));
        *(uint2*)&Xl[node * XS + col] = make_uint2(*(unsigned*)&p0, *(unsigned*)&p1);
    }
    __syncthreads();
    int v = tid & 255;
    int j0 = (tid >> 8) * 32;
    // gather S[64] = sum of in-neighbor rows (both j-half threads duplicate)
    float S[64];
    #pragma unroll
    for (int k = 0; k < 64; ++k) S[k] = 0.f;
    {
        const int* colp = (const int*)(ws + WCOLP);
        const int* rows = (const int*)(ws + WROWS);
        int e1 = colp[v + 1];
        for (int e = colp[v]; e < e1; ++e) {
            int r = rows[e];
            const uint2* xp = (const uint2*)(Xl + r * XS);
            #pragma unroll
            for (int w = 0; w < 16; ++w) {
                uint2 u = xp[w];
                S[4 * w]     += blo(u.x);
                S[4 * w + 1] += bhi(u.x);
                S[4 * w + 2] += blo(u.y);
                S[4 * w + 3] += bhi(u.y);
            }
        }
    }
    float dinv = ws[WDINV + v];
    float sel  = ws[WSEL + v];
    const float* Mb = (sel > 0.5f) ? (ws + WRQ) : m2W;  // m2W rows 0..63 = W2a
    float acc[32];
    {
        const float* bv = ws + WBIAS + v * 64 + j0;
        #pragma unroll
        for (int j = 0; j < 32; ++j) acc[j] = bv[j];
    }
    // GEMV: x part (K=64)
    {
        const uint2* xrow = (const uint2*)(Xl + v * XS);
        #pragma unroll
        for (int kk = 0; kk < 16; ++kk) {
            uint2 u = xrow[kk];
            float xv[4] = { blo(u.x), bhi(u.x), blo(u.y), bhi(u.y) };
            #pragma unroll
            for (int s = 0; s < 4; ++s) {
                const float* Mr = Mb + (4 * kk + s) * 64 + j0;
                #pragma unroll
                for (int j = 0; j < 32; j += 4) {
                    float4 m = *(const float4*)(Mr + j);
                    acc[j]     = fmaf(xv[s], m.x, acc[j]);
                    acc[j + 1] = fmaf(xv[s], m.y, acc[j + 1]);
                    acc[j + 2] = fmaf(xv[s], m.z, acc[j + 2]);
                    acc[j + 3] = fmaf(xv[s], m.w, acc[j + 3]);
                }
            }
        }
    }
    // GEMV: S part (K=64), dinv folded into the vector
    {
        const float* Pm = ws + WP;
        #pragma unroll
        for (int k = 0; k < 64; ++k) {
            float sv = dinv * S[k];
            const float* Pr = Pm + k * 64 + j0;
            #pragma unroll
            for (int j = 0; j < 32; j += 4) {
                float4 p = *(const float4*)(Pr + j);
                acc[j]     = fmaf(sv, p.x, acc[j]);
                acc[j + 1] = fmaf(sv, p.y, acc[j + 1]);
                acc[j + 2] = fmaf(sv, p.z, acc[j + 2]);
                acc[j + 3] = fmaf(sv, p.w, acc[j + 3]);
            }
        }
    }
    float* og = out + (tg * N_ + v) * 64 + j0;
    #pragma unroll
    for (int j = 0; j < 32; j += 4) {
        *(float4*)(og + j) = make_float4(acc[j], acc[j + 1], acc[j + 2], acc[j + 3]);
    }
}

extern "C" void kernel_launch(void* const* d_in, const int* in_sizes, int n_in,
                              void* d_out, int out_size, void* d_ws, size_t ws_size,
                              hipStream_t stream) {
    const float* aqi  = (const float*)d_in[0];
    const int*   conn = (const int*)d_in[1];
    const float* cw   = (const float*)d_in[2];
    const float* embW = (const float*)d_in[3];
    const float* embB = (const float*)d_in[4];
    const float* Wih  = (const float*)d_in[5];
    const float* Whh  = (const float*)d_in[6];
    const float* bih  = (const float*)d_in[7];
    const float* bhh  = (const float*)d_in[8];
    const float* m1W  = (const float*)d_in[9];
    const float* m1b  = (const float*)d_in[10];
    const float* m2W  = (const float*)d_in[11];
    const float* m2b  = (const float*)d_in[12];
    float* ws  = (float*)d_ws;
    float* out = (float*)d_out;

    k_prep<<<dim3(9), dim3(256), 0, stream>>>(conn, cw, Wih, embW, embB, bih, bhh,
                                              m1W, m1b, m2W, m2b, ws);
    k_lstm<<<dim3(512), dim3(256), 0, stream>>>(aqi, Whh, ws, out);
    k_graph<<<dim3(T_), dim3(512), 0, stream>>>(ws, m2W, out);
}

// Round 7
// 255.717 us; speedup vs baseline: 1.3331x; 1.3331x over previous
//
#include <hip/hip_runtime.h>
#include <hip/hip_bf16.h>

// Problem constants (fixed by reference)
#define B_ 16
#define L_ 24
#define N_ 256
#define E_ 4096
#define T_ (B_ * L_)   // 384 graphs

// All tensors float32. Output [B,L,N,64] f32 = 25.2 MB.
// X (LSTM h states, [T,N,64] f32) lives in d_out; k_graph overwrites its own
// tile in place. ws holds folded tables only (~140 KB).
constexpr int WP    = 0;                   // P = W1a@W2b  (64x64)
constexpr int WRQ   = WP + 4096;           // RQ = W2a + Q (64x64), Q = W1b@W2b
constexpr int WRM   = WRQ + 4096;          // Q alone (for rare sel==0 correction)
constexpr int WBIAS = WRM + 4096;          // biasv [256][64]
constexpr int WALPHA= WBIAS + 16384;       // alpha[256]
constexpr int WBETA = WALPHA + 256;        // beta[256]
constexpr int WDINV = WBETA + 256;         // 1/max(cnt,1) [256]
constexpr int WSEL  = WDINV + 256;         // cnt>0 ? 1 : 0 [256]
constexpr int WSW   = WSEL + 256;          // sw0[256], sw1[256]
constexpr int WCNTF = WSW + 512;           // cnt as float [256]
constexpr int WCOLP = WCNTF + 256;         // 257 ints (CSR col ptr)
constexpr int WROWS = WCOLP + 260;         // 4096 ints (row node per edge, grouped by col)

__device__ __forceinline__ float sigm(float x) { return 1.f / (1.f + __expf(-x)); }
__device__ __forceinline__ float tanh_(float x) { return 2.f / (1.f + __expf(-2.f * x)) - 1.f; }
__device__ __forceinline__ float bcast(float v, int lane) {
    return __int_as_float(__builtin_amdgcn_readlane(__float_as_int(v), lane));
}
__device__ __forceinline__ float blo(unsigned u) { return __uint_as_float(u << 16); }
__device__ __forceinline__ float bhi(unsigned u) { return __uint_as_float(u & 0xffff0000u); }

// ---- K1 fused prep: block 0 = graph tables + alpha/beta + U + biasv;
// ----                blocks 1..8 = P / RQ / Q weight products.
__global__ __launch_bounds__(256) void k_prep(
    const int* __restrict__ conn, const float* __restrict__ cw,
    const float* __restrict__ Wih, const float* __restrict__ embW,
    const float* __restrict__ embB, const float* __restrict__ bih,
    const float* __restrict__ bhh, const float* __restrict__ m1W,
    const float* __restrict__ m1b, const float* __restrict__ m2W,
    const float* __restrict__ m2b, float* __restrict__ ws) {
    int t = threadIdx.x, blk = blockIdx.x;
    if (blk > 0) {
        // ---- P = W1a@W2b (blk 1..4), RQ/Q (blk 5..8) ----
        __shared__ float sB[64 * 64];   // W2b = m2W rows 64..127
        bool isP = blk <= 4;
        int kbase = ((blk - 1) & 3) * 16;
        #pragma unroll
        for (int i = 0; i < 16; ++i) sB[t + 256 * i] = m2W[64 * 64 + t + 256 * i];
        __syncthreads();
        int j = t & 63, kl = t >> 6;
        #pragma unroll
        for (int r = 0; r < 4; ++r) {
            int k = kbase + kl * 4 + r;
            const float* arow = m1W + (isP ? k : (64 + k)) * 64;
            float acc = 0.f;
            #pragma unroll
            for (int m = 0; m < 64; m += 4) {
                float4 a4 = *(const float4*)(arow + m);
                acc = fmaf(a4.x, sB[m * 64 + j], acc);
                acc = fmaf(a4.y, sB[(m + 1) * 64 + j], acc);
                acc = fmaf(a4.z, sB[(m + 2) * 64 + j], acc);
                acc = fmaf(a4.w, sB[(m + 3) * 64 + j], acc);
            }
            if (isP) {
                ws[WP + k * 64 + j] = acc;
            } else {
                ws[WRM + k * 64 + j] = acc;                       // Q
                ws[WRQ + k * 64 + j] = acc + m2W[k * 64 + j];     // W2a + Q
            }
        }
        return;
    }
    // ---- block 0: tables ----
    __shared__ int s_cnt[N_];
    __shared__ float s_sw0[N_], s_sw1[N_];
    __shared__ int s_pos[N_];
    __shared__ float sU[3 * 64];
    __shared__ int s_wsum[4];
    s_cnt[t] = 0; s_sw0[t] = 0.f; s_sw1[t] = 0.f;
    __syncthreads();
    for (int e = t; e < E_; e += 256) {
        int c = conn[E_ + e] & 255;
        atomicAdd(&s_cnt[c], 1);
        atomicAdd(&s_sw0[c], cw[2 * e]);
        atomicAdd(&s_sw1[c], cw[2 * e + 1]);
    }
    __syncthreads();
    // exclusive prefix sum over 256 via wave shfl scan + wave offsets
    int lane = t & 63, wv = t >> 6;
    int val = s_cnt[t];
    int inc = val;
    #pragma unroll
    for (int d = 1; d < 64; d <<= 1) {
        int y = __shfl_up(inc, d);
        if (lane >= d) inc += y;
    }
    if (lane == 63) s_wsum[wv] = inc;
    __syncthreads();
    int wadd = 0;
    for (int w = 0; w < wv; ++w) wadd += s_wsum[w];
    int excl = wadd + inc - val;
    int* colp = (int*)(ws + WCOLP);
    colp[t] = excl;
    if (t == 0) colp[N_] = E_;
    s_pos[t] = excl;
    int cnt = val;
    ws[WCNTF + t] = (float)cnt;
    ws[WDINV + t] = 1.f / (float)(cnt > 1 ? cnt : 1);
    ws[WSEL + t]  = cnt > 0 ? 1.f : 0.f;
    ws[WSW + t]        = s_sw0[t];
    ws[WSW + N_ + t]   = s_sw1[t];
    // LSTM input collapse: xg[g] = aqi*alpha[g] + beta[g]
    float a = 0.f, b = 0.f;
    #pragma unroll
    for (int i = 0; i < 16; ++i) {
        float w = Wih[t * 16 + i];
        a += w * embW[i];
        b += w * embB[i];
    }
    ws[WALPHA + t] = a;
    ws[WBETA + t]  = b + bih[t] + bhh[t];
    __syncthreads();   // all s_pos[] initialized before rows fill
    int* rows = (int*)(ws + WROWS);
    for (int e = t; e < E_; e += 256) {
        int c = conn[E_ + e] & 255;
        int p = atomicAdd(&s_pos[c], 1);
        rows[p] = conn[e] & 255;
    }
    // U vectors: U0 = W1c0@W2b, U1 = W1c1@W2b, U2 = b1@W2b
    if (t < 192) {
        int part = t >> 6, j = t & 63;
        float acc = 0.f;
        #pragma unroll 8
        for (int m = 0; m < 64; ++m) {
            float w = (part == 0) ? m1W[128 * 64 + m]
                    : (part == 1) ? m1W[129 * 64 + m] : m1b[m];
            acc = fmaf(w, m2W[(64 + m) * 64 + j], acc);
        }
        sU[part * 64 + j] = acc;
    }
    __syncthreads();
    // biasv[v][j] = dinv_v*(sw0_v*U0[j] + sw1_v*U1[j] + cnt_v*U2[j]) + b2[j]
    {
        int j = t & 63;
        float u0 = sU[j], u1 = sU[64 + j], u2 = sU[128 + j];
        float b2j = m2b[j];
        int vb = t >> 6;
        #pragma unroll 8
        for (int i = 0; i < 64; ++i) {
            int v = vb + i * 4;
            int cv = s_cnt[v];
            float dv = 1.f / (float)(cv > 1 ? cv : 1);
            float bb = s_sw0[v] * u0 + s_sw1[v] * u1 + (float)cv * u2;
            ws[WBIAS + v * 64 + j] = dv * bb + b2j;
        }
    }
}

// ---------------- K2: LSTM. wave = 2 sequences, lane = hidden dim -----------
// (unchanged from round 5 — known-good; counters next round will size it)
__global__ __launch_bounds__(256, 2) void k_lstm(
    const float* __restrict__ aqi, const float* __restrict__ Whh,
    const float* __restrict__ ws, float* __restrict__ xout) {
    __shared__ float Wl[16384];   // Wl[hp*256 + j*4 + k] = W_hh[(k*64+j)*64+hp]
    int t = threadIdx.x;
    #pragma unroll
    for (int i = 0; i < 64; ++i) {
        int idx = t + i * 256;
        int hp = idx >> 8, rem = idx & 255;
        int j = rem >> 2, k = rem & 3;
        Wl[idx] = Whh[(k * 64 + j) * 64 + hp];
    }
    __syncthreads();
    int wave = t >> 6, lane = t & 63;
    int s0 = (blockIdx.x * 4 + wave) * 2;   // sequence = b*256 + n
    int bA = s0 >> 8, nA = s0 & 255;
    int bB = (s0 + 1) >> 8, nB = (s0 + 1) & 255;
    float a0 = ws[WALPHA + lane], a1 = ws[WALPHA + 64 + lane];
    float a2 = ws[WALPHA + 128 + lane], a3 = ws[WALPHA + 192 + lane];
    float e0 = ws[WBETA + lane], e1 = ws[WBETA + 64 + lane];
    float e2 = ws[WBETA + 128 + lane], e3 = ws[WBETA + 192 + lane];
    float hA = 0.f, cA = 0.f, hB = 0.f, cB = 0.f;
    for (int l = 0; l < L_; ++l) {
        float xA = aqi[(bA * L_ + l) * N_ + nA];
        float xB = aqi[(bB * L_ + l) * N_ + nB];
        float g0A = fmaf(xA, a0, e0), g1A = fmaf(xA, a1, e1);
        float g2A = fmaf(xA, a2, e2), g3A = fmaf(xA, a3, e3);
        float g0B = fmaf(xB, a0, e0), g1B = fmaf(xB, a1, e1);
        float g2B = fmaf(xB, a2, e2), g3B = fmaf(xB, a3, e3);
        if (l > 0) {
            #pragma unroll
            for (int hp = 0; hp < 64; ++hp) {
                float hvA = bcast(hA, hp);
                float hvB = bcast(hB, hp);
                const float4 w = *(const float4*)&Wl[hp * 256 + lane * 4];
                g0A = fmaf(hvA, w.x, g0A); g1A = fmaf(hvA, w.y, g1A);
                g2A = fmaf(hvA, w.z, g2A); g3A = fmaf(hvA, w.w, g3A);
                g0B = fmaf(hvB, w.x, g0B); g1B = fmaf(hvB, w.y, g1B);
                g2B = fmaf(hvB, w.z, g2B); g3B = fmaf(hvB, w.w, g3B);
            }
        }
        float iA = sigm(g0A), fA = sigm(g1A), GA = tanh_(g2A), oA = sigm(g3A);
        cA = fmaf(fA, cA, iA * GA); hA = oA * tanh_(cA);
        float iB = sigm(g0B), fB = sigm(g1B), GB = tanh_(g2B), oB = sigm(g3B);
        cB = fmaf(fB, cB, iB * GB); hB = oB * tanh_(cB);
        xout[((bA * L_ + l) * N_ + nA) * 64 + lane] = hA;
        xout[((bB * L_ + l) * N_ + nB) * 64 + lane] = hB;
    }
}

// ---------------- K4: per-graph GNN, S-space gather, no spills --------------
// out[v] = biasv + x[v]@RQ + (dinv*S[v])@P  (− x[v]@Q iff cnt==0; ~never)
// 256 threads = 1 thread/node, acc[64] f32, S[64] f32 (S dies before x-GEMV).
constexpr int XS = 66;  // bf16 LDS row stride: 33 words (odd -> full bank spread)

__global__ __launch_bounds__(256, 2) void k_graph(
    const float* __restrict__ ws, const float* __restrict__ m2W,
    float* __restrict__ out) {
    __shared__ __hip_bfloat16 Xl[N_ * XS];   // 33.8 KB
    int tg = blockIdx.x;
    int tid = threadIdx.x;
    // stage this graph's X tile (16384 f32 = 4096 float4) into bf16 LDS
    const float4* src = (const float4*)(out + tg * (N_ * 64));
    #pragma unroll
    for (int it = 0; it < 16; ++it) {
        int idx = tid + it * 256;
        float4 d = src[idx];
        int node = idx >> 4, col = (idx & 15) * 4;
        __hip_bfloat162 p0 = __halves2bfloat162(__float2bfloat16(d.x), __float2bfloat16(d.y));
        __hip_bfloat162 p1 = __halves2bfloat162(__float2bfloat16(d.z), __float2bfloat16(d.w));
        unsigned* dst = (unsigned*)&Xl[node * XS + col];   // 4B-aligned (132B rows)
        dst[0] = *(unsigned*)&p0;
        dst[1] = *(unsigned*)&p1;
    }
    __syncthreads();
    int v = tid;
    // ---- gather S[64] = sum of in-neighbor x rows ----
    float S[64];
    #pragma unroll
    for (int k = 0; k < 64; ++k) S[k] = 0.f;
    {
        const int* colp = (const int*)(ws + WCOLP);
        const int* rows = (const int*)(ws + WROWS);
        int e1 = colp[v + 1];
        for (int e = colp[v]; e < e1; ++e) {
            int r = rows[e];
            const unsigned* xp = (const unsigned*)(Xl + r * XS);
            #pragma unroll
            for (int w = 0; w < 32; ++w) {
                unsigned u = xp[w];
                S[2 * w]     += blo(u);
                S[2 * w + 1] += bhi(u);
            }
        }
    }
    float dinv = ws[WDINV + v];
    float sel  = ws[WSEL + v];
    float acc[64];
    {
        const float* bv = ws + WBIAS + v * 64;
        #pragma unroll
        for (int j = 0; j < 64; j += 4) {
            float4 b4 = *(const float4*)(bv + j);
            acc[j] = b4.x; acc[j + 1] = b4.y; acc[j + 2] = b4.z; acc[j + 3] = b4.w;
        }
    }
    // ---- S part first (S dies here): acc += (dinv*S) @ P ----
    {
        const float* Pm = ws + WP;
        #pragma unroll 4
        for (int k = 0; k < 64; ++k) {
            float sv = dinv * S[k];
            const float* Pr = Pm + k * 64;
            #pragma unroll
            for (int j = 0; j < 64; j += 4) {
                float4 p = *(const float4*)(Pr + j);
                acc[j]     = fmaf(sv, p.x, acc[j]);
                acc[j + 1] = fmaf(sv, p.y, acc[j + 1]);
                acc[j + 2] = fmaf(sv, p.z, acc[j + 2]);
                acc[j + 3] = fmaf(sv, p.w, acc[j + 3]);
            }
        }
    }
    // ---- x part: acc += x[v] @ RQ ----
    {
        const unsigned* xrow = (const unsigned*)(Xl + v * XS);
        const float* Mm = ws + WRQ;
        #pragma unroll 4
        for (int kk = 0; kk < 32; ++kk) {
            unsigned u = xrow[kk];
            float x0 = blo(u), x1 = bhi(u);
            const float* M0 = Mm + (2 * kk) * 64;
            const float* M1 = M0 + 64;
            #pragma unroll
            for (int j = 0; j < 64; j += 4) {
                float4 m0 = *(const float4*)(M0 + j);
                float4 m1 = *(const float4*)(M1 + j);
                acc[j]     = fmaf(x0, m0.x, fmaf(x1, m1.x, acc[j]));
                acc[j + 1] = fmaf(x0, m0.y, fmaf(x1, m1.y, acc[j + 1]));
                acc[j + 2] = fmaf(x0, m0.z, fmaf(x1, m1.z, acc[j + 2]));
                acc[j + 3] = fmaf(x0, m0.w, fmaf(x1, m1.w, acc[j + 3]));
            }
        }
    }
    // ---- rare correction: cnt==0 nodes use W2a, not W2a+Q ----
    if (sel < 0.5f) {
        const unsigned* xrow = (const unsigned*)(Xl + v * XS);
        const float* Qm = ws + WRM;
        for (int kk = 0; kk < 32; ++kk) {
            unsigned u = xrow[kk];
            float x0 = blo(u), x1 = bhi(u);
            const float* Q0 = Qm + (2 * kk) * 64;
            const float* Q1 = Q0 + 64;
            for (int j = 0; j < 64; ++j)
                acc[j] -= x0 * Q0[j] + x1 * Q1[j];
        }
    }
    float* og = out + (tg * N_ + v) * 64;
    #pragma unroll
    for (int j = 0; j < 64; j += 4) {
        *(float4*)(og + j) = make_float4(acc[j], acc[j + 1], acc[j + 2], acc[j + 3]);
    }
}

extern "C" void kernel_launch(void* const* d_in, const int* in_sizes, int n_in,
                              void* d_out, int out_size, void* d_ws, size_t ws_size,
                              hipStream_t stream) {
    const float* aqi  = (const float*)d_in[0];
    const int*   conn = (const int*)d_in[1];
    const float* cw   = (const float*)d_in[2];
    const float* embW = (const float*)d_in[3];
    const float* embB = (const float*)d_in[4];
    const float* Wih  = (const float*)d_in[5];
    const float* Whh  = (const float*)d_in[6];
    const float* bih  = (const float*)d_in[7];
    const float* bhh  = (const float*)d_in[8];
    const float* m1W  = (const float*)d_in[9];
    const float* m1b  = (const float*)d_in[10];
    const float* m2W  = (const float*)d_in[11];
    const float* m2b  = (const float*)d_in[12];
    float* ws  = (float*)d_ws;
    float* out = (float*)d_out;

    k_prep<<<dim3(9), dim3(256), 0, stream>>>(conn, cw, Wih, embW, embB, bih, bhh,
                                              m1W, m1b, m2W, m2b, ws);
    k_lstm<<<dim3(512), dim3(256), 0, stream>>>(aqi, Whh, ws, out);
    k_graph<<<dim3(T_), dim3(256), 0, stream>>>(ws, m2W, out);
}